// Round 5
// baseline (174.394 us; speedup 1.0000x reference)
//
#include <hip/hip_runtime.h>
#include <hip/hip_bf16.h>
#include <stdint.h>

typedef __bf16 bf16x8 __attribute__((ext_vector_type(8)));
typedef uint16_t u16x8 __attribute__((ext_vector_type(8)));
typedef float f32x16 __attribute__((ext_vector_type(16)));

// DIMS = 256 ->128 ->256 ->512 ->256 ->128 ->64 ->32 ->16 ->10
static constexpr int KD[9]    = {256,128,256,512,256,128,64,32,16};   // layer input width
static constexpr int ND[9]    = {128,256,512,256,128,64,32,16,10};   // layer output width
static constexpr int WOFF[10] = {0,32768,65536,196608,327680,360448,368640,370688,371712,372224};
static constexpr int BOFF[10] = {0,128,384,896,1152,1280,1344,1376,1408,1440};
static constexpr int WTOT = 372224;   // bf16 elements of fragment-ordered weights in ws
static constexpr int BTOT = 1440;     // padded bias floats in ws

__device__ __forceinline__ uint16_t f2bf(float f) {
  uint32_t u = __builtin_bit_cast(uint32_t, f);
  return (uint16_t)((u + 0x7fffu + ((u >> 16) & 1u)) >> 16);   // RNE
}

// swizzle mask for a row-major LDS tile with rowbytes = width*2
constexpr int swzm(int width) {
  return (width >= 128) ? 15 : (width == 64) ? 7 : (width == 32) ? 3 : 1;
}

// ---------------- prep: W[K][N] fp32 -> B-fragment-ordered bf16 (+ padded bias) ----------
// Layout per layer: flat = ((ct*KS + ks)*64 + lane)*8 + j
//   col = ct*32 + (lane&31), k = ks*16 + (lane>>5)*8 + j
// so a wave's B-load for (ct,ks) is 64 lanes x 16B fully contiguous (1KB).
struct PrepArgs {
  const float* W[9];
  const float* b[9];
  uint16_t* wt;
  float* bias;
};

__global__ void prep_kernel(PrepArgs a) {
  int idx = blockIdx.x * 256 + threadIdx.x;
  if (idx < WTOT) {
#pragma unroll
    for (int l = 0; l < 9; ++l) {
      if (idx >= WOFF[l] && idx < WOFF[l + 1]) {
        const int K = KD[l], N = ND[l], KS = KD[l] / 16;
        int local = idx - WOFF[l];
        int j    = local & 7;
        int g    = local >> 3;
        int lane = g & 63;
        int gg   = g >> 6;
        int ks   = gg % KS;
        int ct   = gg / KS;
        int n = ct * 32 + (lane & 31);
        int k = ks * 16 + (lane >> 5) * 8 + j;
        float v = (n < N) ? a.W[l][(size_t)k * N + n] : 0.0f;
        a.wt[idx] = f2bf(v);
      }
    }
  } else if (idx < WTOT + BTOT) {
    int bidx = idx - WTOT;
#pragma unroll
    for (int l = 0; l < 9; ++l) {
      if (bidx >= BOFF[l] && bidx < BOFF[l + 1]) {
        int n = bidx - BOFF[l];
        a.bias[bidx] = (n < ND[l]) ? a.b[l][n] : 0.0f;
      }
    }
  }
}

// ---------------- fused MLP ----------------
struct MainArgs {
  const float* x;
  const float* m[8];
  const uint16_t* wt;
  const float* bias;
  float* out;
};

// A-frag (32x32x16 bf16): lane holds row=lane&31, k = (lane>>5)*8 + [0..7]
// B-frag:                  lane holds col=lane&31, k = (lane>>5)*8 + [0..7]
// C/D  :                   col=lane&31, row=(reg&3)+8*(reg>>2)+4*(lane>>5)   [m74/m101]

// Prefetch bias + dropout masks for layer L into registers (issued ~1 layer early).
template <int L, int TNE, int CTOFF>
__device__ __forceinline__ void mask_pf(const MainArgs& a, int row0, int wid, int lane,
                                        float (&mv)[2][16], float (&bv)[2]) {
  constexpr int N   = ND[L];
  constexpr int NB  = (TNE >= 4) ? TNE / 4 : 1;
  constexpr int ACT = (TNE >= 4) ? 4 : TNE;
  if (wid >= ACT) return;
  const int r  = lane & 31;
  const int kg = lane >> 5;
#pragma unroll
  for (int i = 0; i < NB; ++i) {
    const int col = (CTOFF + wid * NB + i) * 32 + r;
    bv[i] = a.bias[BOFF[L] + col];
    if constexpr (L < 8) {
      const int mc = (N % 32) ? (col < N ? col : N - 1) : col;
      const float* mrow = a.m[L] + mc;
#pragma unroll
      for (int t = 0; t < 16; ++t) {
        const int rit = (t & 3) + ((t >> 2) << 3) + (kg << 2);
        mv[i][t] = mrow[(size_t)(row0 + rit) * N];
      }
    }
  }
}

// TNE = 32-col tiles computed; CTOFF = tile offset (split L2). SIN: K split across
// two half-buffers. PREBAR: barrier before epilogue write (write aliases input).
// pf() is invoked right after the LAST B-load issue of the K-loop, so the loads it
// issues (next layer's masks, HBM) are never drained by this layer's vmcnt waits.
template <int L, int TNE, int CTOFF, bool LAST, bool SIN, bool PREBAR, int OSTR, typename PF>
__device__ __forceinline__ void layer_fn(const MainArgs& a, int row0, int wid, int lane,
                                         const char* in0, const char* in1, char* outb,
                                         const float (&mv)[2][16], const float (&bv)[2],
                                         PF&& pf) {
  constexpr int K   = KD[L];
  constexpr int N   = ND[L];
  constexpr int KS  = K / 16;
  constexpr int NB  = (TNE >= 4) ? TNE / 4 : 1;
  constexpr int ACT = (TNE >= 4) ? 4 : TNE;
  constexpr int SWZI = swzm(K);
  constexpr int SWZO = swzm(OSTR);
  constexpr bool DUAL = (NB == 1 && KS >= 2);
  constexpr int D   = 4;                      // B-prefetch ring depth
  // Ring invariant: write slot (ks+PRE)%D must differ from read slot ks%D,
  // i.e. PRE % D != 0. (Round-4 bug: PRE==D==4 made every MFMA consume the
  // freshly-issued ks+4 load.) PRE = D-1 keeps slots distinct for all KS.
  constexpr int PRE = (KS < D - 1) ? KS : D - 1;

  const int r  = lane & 31;
  const int kg = lane >> 5;
  const int ct0 = wid * NB;
  const bool act = (wid < ACT);

  f32x16 acc[NB];
  f32x16 acc2;

  if (act) {
#pragma unroll
    for (int i = 0; i < NB; ++i)
#pragma unroll
      for (int t = 0; t < 16; ++t) acc[i][t] = 0.0f;
    if constexpr (DUAL) {
#pragma unroll
      for (int t = 0; t < 16; ++t) acc2[t] = 0.0f;
    }

    // fragment-ordered B base: wave's load for (tile i, ks) is contiguous 1KB
    const uint16_t* wbase = a.wt + WOFF[L]
        + ((size_t)(CTOFF + ct0) * KS * 64 + lane) * 8;

    bf16x8 bb[D][NB];
#pragma unroll
    for (int j = 0; j < PRE; ++j)
#pragma unroll
      for (int i = 0; i < NB; ++i)
        bb[j][i] = *(const bf16x8*)(wbase + (size_t)i * KS * 512 + (size_t)j * 512);

#pragma unroll
    for (int ks = 0; ks < KS; ++ks) {
      if (ks == KS - PRE) pf();               // after the last B-load issue
      if (ks + PRE < KS) {
#pragma unroll
        for (int i = 0; i < NB; ++i)
          bb[(ks + PRE) % D][i] =
              *(const bf16x8*)(wbase + (size_t)i * KS * 512 + (size_t)(ks + PRE) * 512);
      }
      bf16x8 av;
      {
        uint32_t byte;
        const char* src;
        if constexpr (SIN) {
          const int kk = (ks < 16) ? ks : ks - 16;
          src = (ks < 16) ? in0 : in1;
          byte = (uint32_t)(r * 256 + kk * 16 + kg * 8) * 2;
          byte ^= (uint32_t)(r & 15) << 4;
        } else {
          src = in0;
          byte = (uint32_t)(r * K + ks * 16 + kg * 8) * 2;
          byte ^= (uint32_t)(r & SWZI) << 4;
        }
        av = *(const bf16x8*)(src + byte);
      }
      if constexpr (DUAL) {
        if ((ks & 1) == 0)
          acc[0] = __builtin_amdgcn_mfma_f32_32x32x16_bf16(av, bb[ks % D][0], acc[0], 0, 0, 0);
        else
          acc2 = __builtin_amdgcn_mfma_f32_32x32x16_bf16(av, bb[ks % D][0], acc2, 0, 0, 0);
      } else {
#pragma unroll
        for (int i = 0; i < NB; ++i)
          acc[i] = __builtin_amdgcn_mfma_f32_32x32x16_bf16(av, bb[ks % D][i], acc[i], 0, 0, 0);
      }
    }
    if constexpr (DUAL) acc[0] += acc2;
  }

  if constexpr (PREBAR) __syncthreads();

  if (act) {
#pragma unroll
    for (int i = 0; i < NB; ++i) {
      const int col = (CTOFF + ct0 + i) * 32 + r;
#pragma unroll
      for (int t = 0; t < 16; ++t) {
        const int rit = (t & 3) + ((t >> 2) << 3) + (kg << 2);
        float v = acc[i][t] + bv[i];
        if constexpr (LAST) {
          if (col < N) a.out[(size_t)(row0 + rit) * N + col] = v;
        } else {
          v = fmaxf(v, 0.0f) * mv[i][t];
          if ((N % 32 == 0) || col < N) {
            uint32_t ob = (uint32_t)(rit * OSTR + (col - CTOFF * 32)) * 2;
            ob ^= (uint32_t)(rit & SWZO) << 4;
            *(uint16_t*)(outb + ob) = f2bf(v);
          }
        }
      }
    }
  }
}

__global__ __launch_bounds__(256, 3) void mlp_kernel(MainArgs a) {
  __shared__ char bufA[16384];
  __shared__ char bufB[16384];

  const int tid = threadIdx.x;
  const int row0 = blockIdx.x * 32;
  const int lane = tid & 63;
  const int wid = tid >> 6;

  float mv0[2][16], mv1[2][16];
  float bv0[2], bv1[2];

  // L0 masks issued first: their HBM latency rides under the x load+stage.
  mask_pf<0, 4, 0>(a, row0, wid, lane, mv0, bv0);

  // stage x: fp32 -> bf16 into bufA (swizzled), coalesced
  {
    const float* xp = a.x + (size_t)row0 * 256;
#pragma unroll
    for (int j = 0; j < 4; ++j) {
      const int cidx = j * 256 + tid;       // float8 chunk id in [0,1024)
      const int rr = cidx >> 5;             // row 0..31
      const int cc = (cidx & 31) << 3;      // col 0..248
      const float4 f0 = *(const float4*)(xp + cidx * 8);
      const float4 f1 = *(const float4*)(xp + cidx * 8 + 4);
      u16x8 h;
      h[0] = f2bf(f0.x); h[1] = f2bf(f0.y); h[2] = f2bf(f0.z); h[3] = f2bf(f0.w);
      h[4] = f2bf(f1.x); h[5] = f2bf(f1.y); h[6] = f2bf(f1.z); h[7] = f2bf(f1.w);
      uint32_t byte = (uint32_t)(rr * 512 + cc * 2) ^ ((uint32_t)(rr & 15) << 4);
      *(u16x8*)(bufA + byte) = h;
    }
  }
  __syncthreads();

  layer_fn<0, 4, 0, false, false, false, 128>(a, row0, wid, lane, bufA, nullptr, bufB, mv0, bv0,
      [&]() { mask_pf<1, 8, 0>(a, row0, wid, lane, mv1, bv1); });
  __syncthreads();
  layer_fn<1, 8, 0, false, false, false, 256>(a, row0, wid, lane, bufB, nullptr, bufA, mv1, bv1,
      [&]() { mask_pf<2, 8, 8>(a, row0, wid, lane, mv0, bv0); });
  __syncthreads();
  // L2 (256->512) split: cols 256-511 -> bufB (free), then cols 0-255 -> bufA
  // (aliases input: PREBAR inside before the write).
  layer_fn<2, 8, 8, false, false, false, 256>(a, row0, wid, lane, bufA, nullptr, bufB, mv0, bv0,
      [&]() { mask_pf<2, 8, 0>(a, row0, wid, lane, mv1, bv1); });
  layer_fn<2, 8, 0, false, false, true,  256>(a, row0, wid, lane, bufA, nullptr, bufA, mv1, bv1,
      [&]() { mask_pf<3, 8, 0>(a, row0, wid, lane, mv0, bv0); });
  __syncthreads();
  // L3 (512->256): K split across bufA (k 0-255) + bufB (k 256-511), write bufA after PREBAR.
  layer_fn<3, 8, 0, false, true,  true,  256>(a, row0, wid, lane, bufA, bufB, bufA, mv0, bv0,
      [&]() { mask_pf<4, 4, 0>(a, row0, wid, lane, mv1, bv1); });
  __syncthreads();
  layer_fn<4, 4, 0, false, false, false, 128>(a, row0, wid, lane, bufA, nullptr, bufB, mv1, bv1,
      [&]() { mask_pf<5, 2, 0>(a, row0, wid, lane, mv0, bv0); });
  __syncthreads();
  layer_fn<5, 2, 0, false, false, false, 64 >(a, row0, wid, lane, bufB, nullptr, bufA, mv0, bv0,
      [&]() { mask_pf<6, 1, 0>(a, row0, wid, lane, mv1, bv1); });
  __syncthreads();
  // L6..L8: only wave 0 active; chain is wave-local -> no barriers needed.
  layer_fn<6, 1, 0, false, false, false, 32 >(a, row0, wid, lane, bufA, nullptr, bufB, mv1, bv1,
      [&]() { mask_pf<7, 1, 0>(a, row0, wid, lane, mv0, bv0); });
  layer_fn<7, 1, 0, false, false, false, 16 >(a, row0, wid, lane, bufB, nullptr, bufA, mv0, bv0,
      [&]() { mask_pf<8, 1, 0>(a, row0, wid, lane, mv1, bv1); });
  layer_fn<8, 1, 0, true,  false, false, 16 >(a, row0, wid, lane, bufA, nullptr, nullptr, mv1, bv1,
      [&]() {});
}

extern "C" void kernel_launch(void* const* d_in, const int* in_sizes, int n_in,
                              void* d_out, int out_size, void* d_ws, size_t ws_size,
                              hipStream_t stream) {
  (void)in_sizes; (void)n_in; (void)out_size; (void)ws_size;

  PrepArgs pa;
  for (int l = 0; l < 9; ++l) {
    pa.W[l] = (const float*)d_in[1 + 2 * l];
    pa.b[l] = (const float*)d_in[2 + 2 * l];
  }
  uint16_t* wt = (uint16_t*)d_ws;
  float* bias = (float*)((char*)d_ws + (size_t)WTOT * 2);
  pa.wt = wt;
  pa.bias = bias;
  prep_kernel<<<dim3((WTOT + BTOT + 255) / 256), dim3(256), 0, stream>>>(pa);

  MainArgs ma;
  ma.x = (const float*)d_in[0];
  for (int i = 0; i < 8; ++i) ma.m[i] = (const float*)d_in[19 + i];
  ma.wt = wt;
  ma.bias = bias;
  ma.out = (float*)d_out;
  mlp_kernel<<<dim3(65536 / 32), dim3(256), 0, stream>>>(ma);
}

// Round 6
// 131.540 us; speedup vs baseline: 1.3258x; 1.3258x over previous
//
#include <hip/hip_runtime.h>
#include <hip/hip_bf16.h>
#include <stdint.h>

typedef __bf16 bf16x8 __attribute__((ext_vector_type(8)));
typedef uint16_t u16x8 __attribute__((ext_vector_type(8)));
typedef float f32x16 __attribute__((ext_vector_type(16)));

// DIMS = 256 ->128 ->256 ->512 ->256 ->128 ->64 ->32 ->16 ->10
static constexpr int KD[9]    = {256,128,256,512,256,128,64,32,16};   // layer input width
static constexpr int ND[9]    = {128,256,512,256,128,64,32,16,10};   // layer output width
static constexpr int WOFF[10] = {0,32768,65536,196608,327680,360448,368640,370688,371712,372224};
static constexpr int BOFF[10] = {0,128,384,896,1152,1280,1344,1376,1408,1440};
static constexpr int WTOT = 372224;   // bf16 elements of fragment-ordered weights in ws
static constexpr int BTOT = 1440;     // padded bias floats in ws

__device__ __forceinline__ uint16_t f2bf(float f) {
  uint32_t u = __builtin_bit_cast(uint32_t, f);
  return (uint16_t)((u + 0x7fffu + ((u >> 16) & 1u)) >> 16);   // RNE
}

// swizzle mask for a row-major LDS tile with rowbytes = width*2
constexpr int swzm(int width) {
  return (width >= 128) ? 15 : (width == 64) ? 7 : (width == 32) ? 3 : 1;
}

// Raw barrier: LDS coherence needs only lgkmcnt(0). Avoids __syncthreads'
// implicit s_waitcnt vmcnt(0) drain, so global prefetches (masks, B-ring)
// stay in flight across layer transitions.
__device__ __forceinline__ void soft_barrier() {
  asm volatile("s_waitcnt lgkmcnt(0)" ::: "memory");
  __builtin_amdgcn_s_barrier();
}

// ---------------- prep: W[K][N] fp32 -> B-fragment-ordered bf16 (+ padded bias) ----------
// Layout per layer: flat = ((ct*KS + ks)*64 + lane)*8 + j
//   col = ct*32 + (lane&31), k = ks*16 + (lane>>5)*8 + j
// so a wave's B-load for (ct,ks) is 64 lanes x 16B fully contiguous (1KB).
struct PrepArgs {
  const float* W[9];
  const float* b[9];
  uint16_t* wt;
  float* bias;
};

__global__ void prep_kernel(PrepArgs a) {
  int idx = blockIdx.x * 256 + threadIdx.x;
  if (idx < WTOT) {
#pragma unroll
    for (int l = 0; l < 9; ++l) {
      if (idx >= WOFF[l] && idx < WOFF[l + 1]) {
        const int K = KD[l], N = ND[l], KS = KD[l] / 16;
        int local = idx - WOFF[l];
        int j    = local & 7;
        int g    = local >> 3;
        int lane = g & 63;
        int gg   = g >> 6;
        int ks   = gg % KS;
        int ct   = gg / KS;
        int n = ct * 32 + (lane & 31);
        int k = ks * 16 + (lane >> 5) * 8 + j;
        float v = (n < N) ? a.W[l][(size_t)k * N + n] : 0.0f;
        a.wt[idx] = f2bf(v);
      }
    }
  } else if (idx < WTOT + BTOT) {
    int bidx = idx - WTOT;
#pragma unroll
    for (int l = 0; l < 9; ++l) {
      if (bidx >= BOFF[l] && bidx < BOFF[l + 1]) {
        int n = bidx - BOFF[l];
        a.bias[bidx] = (n < ND[l]) ? a.b[l][n] : 0.0f;
      }
    }
  }
}

// ---------------- fused MLP ----------------
struct MainArgs {
  const float* x;
  const float* m[8];
  const uint16_t* wt;
  const float* bias;
  float* out;
};

// Mask/bias prefetch state. Ext-vector members = SSA values, never
// addressable -> lives in VGPRs (round-5 spilled float[2][16] arrays).
struct MS {
  f32x16 m0, m1;   // dropout masks for wave's tile 0 / tile 1
  float b0, b1;    // bias for tile 0 / tile 1
};

// A-frag (32x32x16 bf16): lane holds row=lane&31, k = (lane>>5)*8 + [0..7]
// B-frag:                  lane holds col=lane&31, k = (lane>>5)*8 + [0..7]
// C/D  :                   col=lane&31, row=(reg&3)+8*(reg>>2)+4*(lane>>5)   [m74/m101]

// Prefetch bias + dropout masks for layer L (issued ~1 layer early, consumed
// at L's epilogue). Returns by value.
template <int L, int TNE, int CTOFF>
__device__ __forceinline__ MS mask_pf(const MainArgs& a, int row0, int wid, int lane) {
  MS s{};
  constexpr int N   = ND[L];
  constexpr int NB  = (TNE >= 4) ? TNE / 4 : 1;
  constexpr int ACT = (TNE >= 4) ? 4 : TNE;
  if (wid >= ACT) return s;
  const int r  = lane & 31;
  const int kg = lane >> 5;
#pragma unroll
  for (int i = 0; i < NB; ++i) {
    const int col = (CTOFF + wid * NB + i) * 32 + r;
    const float b = a.bias[BOFF[L] + col];
    if (i == 0) s.b0 = b; else s.b1 = b;
    if constexpr (L < 8) {
      const int mc = (N % 32) ? (col < N ? col : N - 1) : col;
      const float* mrow = a.m[L] + mc;
#pragma unroll
      for (int t = 0; t < 16; ++t) {
        const int rit = (t & 3) + ((t >> 2) << 3) + (kg << 2);
        const float mval = mrow[(size_t)(row0 + rit) * N];
        if (i == 0) s.m0[t] = mval; else s.m1[t] = mval;
      }
    }
  }
  return s;
}

// TNE = 32-col tiles computed; CTOFF = tile offset (split L2). SIN: K split across
// two half-buffers. PREBAR: barrier before epilogue write (write aliases input).
// pf() (returns next layer's MS) is invoked right after the LAST B-load issue, so
// no later-issued load's vmcnt wait drains it within this layer; with soft
// barriers it stays in flight until the next layer's first B wait.
template <int L, int TNE, int CTOFF, bool LAST, bool SIN, bool PREBAR, int OSTR, typename PF>
__device__ __forceinline__ MS layer_fn(const MainArgs& a, int row0, int wid, int lane,
                                       const char* in0, const char* in1, char* outb,
                                       MS ms, PF&& pf) {
  constexpr int K   = KD[L];
  constexpr int N   = ND[L];
  constexpr int KS  = K / 16;
  constexpr int NB  = (TNE >= 4) ? TNE / 4 : 1;
  constexpr int ACT = (TNE >= 4) ? 4 : TNE;
  constexpr int SWZI = swzm(K);
  constexpr int SWZO = swzm(OSTR);
  constexpr bool DUAL = (NB == 1 && KS >= 2);
  constexpr int D   = 3;                      // B-prefetch ring depth
  // Ring invariant: PRE % D != 0 so write slot (ks+PRE)%D != read slot ks%D.
  constexpr int PRE = (KS < D - 1) ? KS : D - 1;

  const int r  = lane & 31;
  const int kg = lane >> 5;
  const int ct0 = wid * NB;
  const bool act = (wid < ACT);

  MS nxt{};
  f32x16 acc[NB];
  f32x16 acc2;

  if (act) {
#pragma unroll
    for (int i = 0; i < NB; ++i)
#pragma unroll
      for (int t = 0; t < 16; ++t) acc[i][t] = 0.0f;
    if constexpr (DUAL) {
#pragma unroll
      for (int t = 0; t < 16; ++t) acc2[t] = 0.0f;
    }

    // fragment-ordered B base: wave's load for (tile i, ks) is contiguous 1KB
    const uint16_t* wbase = a.wt + WOFF[L]
        + ((size_t)(CTOFF + ct0) * KS * 64 + lane) * 8;

    bf16x8 bb[D][NB];
#pragma unroll
    for (int j = 0; j < PRE; ++j)
#pragma unroll
      for (int i = 0; i < NB; ++i)
        bb[j][i] = *(const bf16x8*)(wbase + (size_t)i * KS * 512 + (size_t)j * 512);

#pragma unroll
    for (int ks = 0; ks < KS; ++ks) {
      if (ks == KS - PRE) nxt = pf();         // after the last B-load issue
      if (ks + PRE < KS) {
#pragma unroll
        for (int i = 0; i < NB; ++i)
          bb[(ks + PRE) % D][i] =
              *(const bf16x8*)(wbase + (size_t)i * KS * 512 + (size_t)(ks + PRE) * 512);
      }
      bf16x8 av;
      {
        uint32_t byte;
        const char* src;
        if constexpr (SIN) {
          const int kk = (ks < 16) ? ks : ks - 16;
          src = (ks < 16) ? in0 : in1;
          byte = (uint32_t)(r * 256 + kk * 16 + kg * 8) * 2;
          byte ^= (uint32_t)(r & 15) << 4;
        } else {
          src = in0;
          byte = (uint32_t)(r * K + ks * 16 + kg * 8) * 2;
          byte ^= (uint32_t)(r & SWZI) << 4;
        }
        av = *(const bf16x8*)(src + byte);
      }
      if constexpr (DUAL) {
        if ((ks & 1) == 0)
          acc[0] = __builtin_amdgcn_mfma_f32_32x32x16_bf16(av, bb[ks % D][0], acc[0], 0, 0, 0);
        else
          acc2 = __builtin_amdgcn_mfma_f32_32x32x16_bf16(av, bb[ks % D][0], acc2, 0, 0, 0);
      } else {
#pragma unroll
        for (int i = 0; i < NB; ++i)
          acc[i] = __builtin_amdgcn_mfma_f32_32x32x16_bf16(av, bb[ks % D][i], acc[i], 0, 0, 0);
      }
    }
    if constexpr (DUAL) acc[0] += acc2;
  }

  if constexpr (PREBAR) soft_barrier();

  if (act) {
#pragma unroll
    for (int i = 0; i < NB; ++i) {
      const int col = (CTOFF + ct0 + i) * 32 + r;
      const float bv = (i == 0) ? ms.b0 : ms.b1;
#pragma unroll
      for (int t = 0; t < 16; ++t) {
        const int rit = (t & 3) + ((t >> 2) << 3) + (kg << 2);
        float v = acc[i][t] + bv;
        if constexpr (LAST) {
          if (col < N) a.out[(size_t)(row0 + rit) * N + col] = v;
        } else {
          const float mk = (i == 0) ? ms.m0[t] : ms.m1[t];
          v = fmaxf(v, 0.0f) * mk;
          if ((N % 32 == 0) || col < N) {
            uint32_t ob = (uint32_t)(rit * OSTR + (col - CTOFF * 32)) * 2;
            ob ^= (uint32_t)(rit & SWZO) << 4;
            *(uint16_t*)(outb + ob) = f2bf(v);
          }
        }
      }
    }
  }
  return nxt;
}

__global__ __launch_bounds__(256, 3) void mlp_kernel(MainArgs a) {
  __shared__ char bufA[16384];
  __shared__ char bufB[16384];

  const int tid = threadIdx.x;
  const int row0 = blockIdx.x * 32;
  const int lane = tid & 63;
  const int wid = tid >> 6;

  // L0 masks issued first: their HBM latency rides under the x load+stage.
  MS s = mask_pf<0, 4, 0>(a, row0, wid, lane);

  // stage x: fp32 -> bf16 into bufA (swizzled), coalesced
  {
    const float* xp = a.x + (size_t)row0 * 256;
#pragma unroll
    for (int j = 0; j < 4; ++j) {
      const int cidx = j * 256 + tid;       // float8 chunk id in [0,1024)
      const int rr = cidx >> 5;             // row 0..31
      const int cc = (cidx & 31) << 3;      // col 0..248
      const float4 f0 = *(const float4*)(xp + cidx * 8);
      const float4 f1 = *(const float4*)(xp + cidx * 8 + 4);
      u16x8 h;
      h[0] = f2bf(f0.x); h[1] = f2bf(f0.y); h[2] = f2bf(f0.z); h[3] = f2bf(f0.w);
      h[4] = f2bf(f1.x); h[5] = f2bf(f1.y); h[6] = f2bf(f1.z); h[7] = f2bf(f1.w);
      uint32_t byte = (uint32_t)(rr * 512 + cc * 2) ^ ((uint32_t)(rr & 15) << 4);
      *(u16x8*)(bufA + byte) = h;
    }
  }
  soft_barrier();

  s = layer_fn<0, 4, 0, false, false, false, 128>(a, row0, wid, lane, bufA, nullptr, bufB, s,
      [&]() { return mask_pf<1, 8, 0>(a, row0, wid, lane); });
  soft_barrier();
  s = layer_fn<1, 8, 0, false, false, false, 256>(a, row0, wid, lane, bufB, nullptr, bufA, s,
      [&]() { return mask_pf<2, 8, 8>(a, row0, wid, lane); });
  soft_barrier();
  // L2 (256->512) split: cols 256-511 -> bufB (free), then cols 0-255 -> bufA
  // (aliases input: PREBAR inside before the write).
  s = layer_fn<2, 8, 8, false, false, false, 256>(a, row0, wid, lane, bufA, nullptr, bufB, s,
      [&]() { return mask_pf<2, 8, 0>(a, row0, wid, lane); });
  s = layer_fn<2, 8, 0, false, false, true,  256>(a, row0, wid, lane, bufA, nullptr, bufA, s,
      [&]() { return mask_pf<3, 8, 0>(a, row0, wid, lane); });
  soft_barrier();
  // L3 (512->256): K split across bufA (k 0-255) + bufB (k 256-511), write bufA after PREBAR.
  s = layer_fn<3, 8, 0, false, true,  true,  256>(a, row0, wid, lane, bufA, bufB, bufA, s,
      [&]() { return mask_pf<4, 4, 0>(a, row0, wid, lane); });
  soft_barrier();
  s = layer_fn<4, 4, 0, false, false, false, 128>(a, row0, wid, lane, bufA, nullptr, bufB, s,
      [&]() { return mask_pf<5, 2, 0>(a, row0, wid, lane); });
  soft_barrier();
  s = layer_fn<5, 2, 0, false, false, false, 64 >(a, row0, wid, lane, bufB, nullptr, bufA, s,
      [&]() { return mask_pf<6, 1, 0>(a, row0, wid, lane); });
  soft_barrier();
  // L6..L8: only wave 0 active; chain is wave-local -> no barriers needed.
  s = layer_fn<6, 1, 0, false, false, false, 32 >(a, row0, wid, lane, bufA, nullptr, bufB, s,
      [&]() { return mask_pf<7, 1, 0>(a, row0, wid, lane); });
  s = layer_fn<7, 1, 0, false, false, false, 16 >(a, row0, wid, lane, bufB, nullptr, bufA, s,
      [&]() { return mask_pf<8, 1, 0>(a, row0, wid, lane); });
  s = layer_fn<8, 1, 0, true,  false, false, 16 >(a, row0, wid, lane, bufA, nullptr, nullptr, s,
      [&]() { return MS{}; });
}

extern "C" void kernel_launch(void* const* d_in, const int* in_sizes, int n_in,
                              void* d_out, int out_size, void* d_ws, size_t ws_size,
                              hipStream_t stream) {
  (void)in_sizes; (void)n_in; (void)out_size; (void)ws_size;

  PrepArgs pa;
  for (int l = 0; l < 9; ++l) {
    pa.W[l] = (const float*)d_in[1 + 2 * l];
    pa.b[l] = (const float*)d_in[2 + 2 * l];
  }
  uint16_t* wt = (uint16_t*)d_ws;
  float* bias = (float*)((char*)d_ws + (size_t)WTOT * 2);
  pa.wt = wt;
  pa.bias = bias;
  prep_kernel<<<dim3((WTOT + BTOT + 255) / 256), dim3(256), 0, stream>>>(pa);

  MainArgs ma;
  ma.x = (const float*)d_in[0];
  for (int i = 0; i < 8; ++i) ma.m[i] = (const float*)d_in[19 + i];
  ma.wt = wt;
  ma.bias = bias;
  ma.out = (float*)d_out;
  mlp_kernel<<<dim3(65536 / 32), dim3(256), 0, stream>>>(ma);
}